// Round 1
// baseline (64186.316 us; speedup 1.0000x reference)
//
#include <hip/hip_runtime.h>

#define B_   64
#define T_   512
#define DI_  512
#define H_   1024
#define G4H  4096

__device__ __forceinline__ float sigm(float x) {
    return 1.0f / (1.0f + __expf(-x));
}
__device__ __forceinline__ float tanh_fast(float x) {
    // tanh(x) = 2*sigmoid(2x) - 1 ; saturates correctly for large |x|
    return 2.0f / (1.0f + __expf(-2.0f * x)) - 1.0f;
}

// xp[tl][b][n] = X[b][t0+tl][:] . Wih[n][:] + (bih[n] + bhh[n])
// grid: (G4H/64, chunk_len), block: 256
__global__ __launch_bounds__(256) void xproj_gemm(
    const float* __restrict__ X, const float* __restrict__ Wih,
    const float* __restrict__ bih, const float* __restrict__ bhh,
    float* __restrict__ xp, int t0)
{
    __shared__ float As[16][64];   // [k][b]
    __shared__ float Bs[16][64];   // [k][n]
    const int tl  = blockIdx.y;
    const int n0  = blockIdx.x * 64;
    const int t   = t0 + tl;
    const int tid = threadIdx.x;
    const int lb  = tid & 63;      // row within tile (b for A, n for B)
    const int lk  = tid >> 6;      // 0..3 -> which k-quad
    const int ty  = tid & 15;      // b-subtile (consecutive lanes vary b)
    const int tx  = tid >> 4;      // n-subtile

    const float* Arow = X + ((size_t)lb * T_ + t) * DI_ + lk * 4;
    const float* Brow = Wih + (size_t)(n0 + lb) * DI_ + lk * 4;

    float acc[4][4];
#pragma unroll
    for (int i = 0; i < 4; ++i)
#pragma unroll
        for (int j = 0; j < 4; ++j) acc[i][j] = 0.f;

    for (int k0 = 0; k0 < DI_; k0 += 16) {
        const float4 av = *(const float4*)(Arow + k0);
        const float4 bv = *(const float4*)(Brow + k0);
        __syncthreads();
        As[lk*4+0][lb] = av.x; As[lk*4+1][lb] = av.y;
        As[lk*4+2][lb] = av.z; As[lk*4+3][lb] = av.w;
        Bs[lk*4+0][lb] = bv.x; Bs[lk*4+1][lb] = bv.y;
        Bs[lk*4+2][lb] = bv.z; Bs[lk*4+3][lb] = bv.w;
        __syncthreads();
#pragma unroll
        for (int k = 0; k < 16; ++k) {
            const float4 a4 = *(const float4*)&As[k][ty*4];
            const float4 b4 = *(const float4*)&Bs[k][tx*4];
            const float ar[4] = {a4.x, a4.y, a4.z, a4.w};
            const float br[4] = {b4.x, b4.y, b4.z, b4.w};
#pragma unroll
            for (int i = 0; i < 4; ++i)
#pragma unroll
                for (int j = 0; j < 4; ++j)
                    acc[i][j] = fmaf(ar[i], br[j], acc[i][j]);
        }
    }

    const int nb = n0 + tx * 4;
    float4 bb4;
    bb4.x = bih[nb+0] + bhh[nb+0];
    bb4.y = bih[nb+1] + bhh[nb+1];
    bb4.z = bih[nb+2] + bhh[nb+2];
    bb4.w = bih[nb+3] + bhh[nb+3];
#pragma unroll
    for (int i = 0; i < 4; ++i) {
        const int b = ty * 4 + i;
        float4 v;
        v.x = acc[i][0] + bb4.x;
        v.y = acc[i][1] + bb4.y;
        v.z = acc[i][2] + bb4.z;
        v.w = acc[i][3] + bb4.w;
        *(float4*)(xp + ((size_t)tl * B_ + b) * G4H + nb) = v;
    }
}

// One timestep: gates = xp[tl] + h @ Whh^T ; gate order i,f,g,o.
// grid: 256 blocks, block: 512 threads = 16 j x 16 b x 2 k-splits.
// State hin/hout/cT transposed [j][b]. h double-buffered (cross-block RAW).
__global__ __launch_bounds__(512) void lstm_step(
    const float* __restrict__ Whh, const float* __restrict__ xp,
    const float* __restrict__ hin, float* __restrict__ hout,
    float* __restrict__ cT, float* __restrict__ hs, float* __restrict__ cs,
    int tl, int t)
{
    const int bid  = blockIdx.x;
    // XCD swizzle: bid%8 ~ XCD; cluster 8 consecutive j-blocks (2 MB of Whh rows)
    // per XCD so W stays resident in that XCD's 4 MB L2 across all 512 steps.
    const int xcd  = bid & 7;
    const int slot = bid >> 3;
    const int jb   = xcd * 8 + (slot & 7);   // 0..63
    const int bb   = slot >> 3;              // 0..3
    const int tid  = threadIdx.x;
    const int jl   = tid & 15;
    const int bl   = (tid >> 4) & 15;
    const int ks   = tid >> 8;               // 0/1, wave-uniform
    const int j    = jb * 16 + jl;
    const int b    = bb * 16 + bl;

    float a0 = 0.f, a1 = 0.f, a2 = 0.f, a3 = 0.f;
    if (ks == 0) {
        const float* xq = xp + ((size_t)tl * B_ + b) * G4H + j;
        a0 = xq[0];
        a1 = xq[H_];
        a2 = xq[2 * H_];
        a3 = xq[3 * H_];
    }
    const float* w0 = Whh + (size_t)j * H_ + ks * 512;
    const float* w1 = w0 + (size_t)H_ * H_;
    const float* w2 = w1 + (size_t)H_ * H_;
    const float* w3 = w2 + (size_t)H_ * H_;
    const float* hp = hin + (size_t)ks * 512 * B_ + b;

#pragma unroll 4
    for (int k = 0; k < 512; k += 4) {
        const float4 wa = *(const float4*)(w0 + k);
        const float4 wb = *(const float4*)(w1 + k);
        const float4 wc = *(const float4*)(w2 + k);
        const float4 wd = *(const float4*)(w3 + k);
        const float h0 = hp[(k+0) * B_];
        const float h1 = hp[(k+1) * B_];
        const float h2 = hp[(k+2) * B_];
        const float h3 = hp[(k+3) * B_];
        a0 = fmaf(wa.x, h0, a0); a1 = fmaf(wb.x, h0, a1);
        a2 = fmaf(wc.x, h0, a2); a3 = fmaf(wd.x, h0, a3);
        a0 = fmaf(wa.y, h1, a0); a1 = fmaf(wb.y, h1, a1);
        a2 = fmaf(wc.y, h1, a2); a3 = fmaf(wd.y, h1, a3);
        a0 = fmaf(wa.z, h2, a0); a1 = fmaf(wb.z, h2, a1);
        a2 = fmaf(wc.z, h2, a2); a3 = fmaf(wd.z, h2, a3);
        a0 = fmaf(wa.w, h3, a0); a1 = fmaf(wb.w, h3, a1);
        a2 = fmaf(wc.w, h3, a2); a3 = fmaf(wd.w, h3, a3);
    }

    __shared__ float red[4][256];
    const int ridx = jl + 16 * bl;
    if (ks == 1) {
        red[0][ridx] = a0; red[1][ridx] = a1;
        red[2][ridx] = a2; red[3][ridx] = a3;
    }
    __syncthreads();
    if (ks == 0) {
        a0 += red[0][ridx]; a1 += red[1][ridx];
        a2 += red[2][ridx]; a3 += red[3][ridx];
        const float ig = sigm(a0);
        const float fg = sigm(a1);
        const float gg = tanh_fast(a2);
        const float og = sigm(a3);
        const size_t cidx = (size_t)j * B_ + b;
        const float cprev = cT[cidx];
        const float cn = fmaf(fg, cprev, ig * gg);
        const float hn = og * tanh_fast(cn);
        cT[cidx]   = cn;
        hout[cidx] = hn;
        const size_t oidx = ((size_t)b * T_ + t) * H_ + j;
        hs[oidx] = hn;
        cs[oidx] = cn;
    }
}

__global__ __launch_bounds__(256) void gather_last(
    const float* __restrict__ hs, const float* __restrict__ cs,
    const int* __restrict__ length,
    float* __restrict__ hl, float* __restrict__ cl)
{
    const int i = blockIdx.x * 256 + threadIdx.x;   // B*H total
    const int b = i >> 10;
    const int j = i & 1023;
    const int tt = length[b] - 1;
    const size_t src = ((size_t)b * T_ + tt) * H_ + j;
    hl[i] = hs[src];
    cl[i] = cs[src];
}

extern "C" void kernel_launch(void* const* d_in, const int* in_sizes, int n_in,
                              void* d_out, int out_size, void* d_ws, size_t ws_size,
                              hipStream_t stream)
{
    const float* X   = (const float*)d_in[0];
    const float* Wih = (const float*)d_in[1];
    const float* Whh = (const float*)d_in[2];
    const float* bih = (const float*)d_in[3];
    const float* bhh = (const float*)d_in[4];
    const int*   len = (const int*)d_in[5];

    float* out = (float*)d_out;
    float* hs = out;
    float* cs = hs + (size_t)B_ * T_ * H_;
    float* hl = cs + (size_t)B_ * T_ * H_;
    float* cl = hl + (size_t)B_ * H_;

    // Workspace layout: hT0 | hT1 | cT | xp-chunk
    float* hT0 = (float*)d_ws;
    float* hT1 = hT0 + (size_t)B_ * H_;
    float* cT  = hT1 + (size_t)B_ * H_;
    float* xp  = cT  + (size_t)B_ * H_;
    const size_t state_bytes = (size_t)3 * B_ * H_ * sizeof(float);
    const size_t per_t       = (size_t)B_ * G4H * sizeof(float);  // 1 MiB per timestep

    int Tc = 1;
    if (ws_size > state_bytes + per_t) {
        size_t m = (ws_size - state_bytes) / per_t;
        Tc = (int)(m > (size_t)T_ ? (size_t)T_ : m);
    }

    hipMemsetAsync(hT0, 0, state_bytes, stream);  // zero hT0, hT1, cT

    for (int t0 = 0; t0 < T_; t0 += Tc) {
        const int clen = (T_ - t0 < Tc) ? (T_ - t0) : Tc;
        dim3 g(G4H / 64, clen);
        xproj_gemm<<<g, 256, 0, stream>>>(X, Wih, bih, bhh, xp, t0);
        for (int tl = 0; tl < clen; ++tl) {
            const int t = t0 + tl;
            const float* hin = (t & 1) ? hT1 : hT0;
            float*      hout = (t & 1) ? hT0 : hT1;
            lstm_step<<<256, 512, 0, stream>>>(Whh, xp, hin, hout, cT, hs, cs, tl, t);
        }
    }
    gather_last<<<(B_ * H_) / 256, 256, 0, stream>>>(hs, cs, len, hl, cl);
}

// Round 2
// 11296.262 us; speedup vs baseline: 5.6821x; 5.6821x over previous
//
#include <hip/hip_runtime.h>

#define B_   64
#define T_   512
#define DI_  512
#define H_   1024
#define G4H  4096
#define KQ   8            // K-splits in the recurrence GEMM
#define BKQ  (H_ / KQ)    // 128 k per block

__device__ __forceinline__ float sigm(float x) {
    return 1.0f / (1.0f + __expf(-x));
}
__device__ __forceinline__ float tanh_fast(float x) {
    return 2.0f / (1.0f + __expf(-2.0f * x)) - 1.0f;
}

// WT[k][r] = Whh[r][k]; Whh is (4096, 1024). Coalesced read + write via LDS tile.
__global__ __launch_bounds__(256) void transpose_whh(
    const float* __restrict__ Whh, float* __restrict__ WT)
{
    __shared__ float tile[64][65];
    const int r0 = blockIdx.x * 64;      // 64 r-tiles
    const int k0 = blockIdx.y * 64;      // 16 k-tiles
    const int tid = threadIdx.x;
    const int lx = tid & 63;
    const int ly = tid >> 6;             // 0..3
#pragma unroll
    for (int i = 0; i < 64; i += 4)
        tile[ly + i][lx] = Whh[(size_t)(r0 + ly + i) * H_ + k0 + lx];
    __syncthreads();
#pragma unroll
    for (int i = 0; i < 64; i += 4)
        WT[(size_t)(k0 + ly + i) * G4H + r0 + lx] = tile[lx][ly + i];
}

// xp[tl][b][n] = X[b][t0+tl][:] . Wih[n][:] + (bih[n]+bhh[n])
// grid: (G4H/64, chunk_len), block 256. All global accesses coalesced.
__global__ __launch_bounds__(256) void xproj_gemm(
    const float* __restrict__ X, const float* __restrict__ Wih,
    const float* __restrict__ bih, const float* __restrict__ bhh,
    float* __restrict__ xp, int t0)
{
    __shared__ float As[16][64];   // [k][b]
    __shared__ float Bs[16][64];   // [k][n]
    const int tl = blockIdx.y;
    const int n0 = blockIdx.x * 64;
    const int t  = t0 + tl;
    const int tid = threadIdx.x;
    // loads: lanes vary k (coalesced 64B per row)
    const int ab = tid >> 2;             // b row 0..63
    const int ak = (tid & 3) * 4;        // k quad
    const int wn = tid >> 2;             // n row 0..63
    const int wk = (tid & 3) * 4;
    // compute/store: lanes vary n (coalesced stores)
    const int by = tid >> 4;             // b-quad 0..15
    const int nx = tid & 15;             // n-quad 0..15

    const float* Ap = X + ((size_t)ab * T_ + t) * DI_ + ak;
    const float* Bp = Wih + (size_t)(n0 + wn) * DI_ + wk;

    float acc[4][4] = {};

    for (int k0 = 0; k0 < DI_; k0 += 16) {
        const float4 av = *(const float4*)(Ap + k0);
        const float4 bv = *(const float4*)(Bp + k0);
        __syncthreads();
        As[ak + 0][ab] = av.x; As[ak + 1][ab] = av.y;
        As[ak + 2][ab] = av.z; As[ak + 3][ab] = av.w;
        Bs[wk + 0][wn] = bv.x; Bs[wk + 1][wn] = bv.y;
        Bs[wk + 2][wn] = bv.z; Bs[wk + 3][wn] = bv.w;
        __syncthreads();
#pragma unroll
        for (int k = 0; k < 16; ++k) {
            const float4 a4 = *(const float4*)&As[k][by * 4];
            const float4 b4 = *(const float4*)&Bs[k][nx * 4];
            const float ar[4] = {a4.x, a4.y, a4.z, a4.w};
            const float br[4] = {b4.x, b4.y, b4.z, b4.w};
#pragma unroll
            for (int i = 0; i < 4; ++i)
#pragma unroll
                for (int j = 0; j < 4; ++j)
                    acc[i][j] = fmaf(ar[i], br[j], acc[i][j]);
        }
    }

    const int nb = n0 + nx * 4;
    const float4 b1 = *(const float4*)(bih + nb);
    const float4 b2 = *(const float4*)(bhh + nb);
    const float4 bb4 = {b1.x + b2.x, b1.y + b2.y, b1.z + b2.z, b1.w + b2.w};
#pragma unroll
    for (int i = 0; i < 4; ++i) {
        const int b = by * 4 + i;
        float4 v;
        v.x = acc[i][0] + bb4.x;
        v.y = acc[i][1] + bb4.y;
        v.z = acc[i][2] + bb4.z;
        v.w = acc[i][3] + bb4.w;
        *(float4*)(xp + ((size_t)tl * B_ + b) * G4H + nb) = v;  // coalesced in n
    }
}

// part[kq][b][n] = sum_{k in kq-slice} h[b][k] * WT[k][n]
// grid (64 nb, KQ kq), block 256. 64n x 64b tile, BK=16.
__global__ __launch_bounds__(256) void step_gemm(
    const float* __restrict__ WT, const float* __restrict__ h,
    float* __restrict__ part)
{
    __shared__ float As[16][64];   // [k][b]
    __shared__ float Bs[16][64];   // [k][n]
    const int n0    = blockIdx.x * 64;
    const int kbase = blockIdx.y * BKQ;
    const int tid = threadIdx.x;
    const int ab = tid >> 2;             // b row
    const int ak = (tid & 3) * 4;
    const int bk = tid >> 4;             // k row 0..15
    const int bn = (tid & 15) * 4;
    const int by = tid >> 4;             // b-quad
    const int nx = tid & 15;             // n-quad

    const float* Ap = h + (size_t)ab * H_ + kbase + ak;
    const float* Bp = WT + (size_t)(kbase + bk) * G4H + n0 + bn;

    float acc[4][4] = {};

    for (int k0 = 0; k0 < BKQ; k0 += 16) {
        const float4 av = *(const float4*)(Ap + k0);
        const float4 bv = *(const float4*)(Bp + (size_t)k0 * G4H);
        __syncthreads();
        As[ak + 0][ab] = av.x; As[ak + 1][ab] = av.y;
        As[ak + 2][ab] = av.z; As[ak + 3][ab] = av.w;
        *(float4*)&Bs[bk][bn] = bv;
        __syncthreads();
#pragma unroll
        for (int k = 0; k < 16; ++k) {
            const float4 a4 = *(const float4*)&As[k][by * 4];
            const float4 b4 = *(const float4*)&Bs[k][nx * 4];
            const float ar[4] = {a4.x, a4.y, a4.z, a4.w};
            const float br[4] = {b4.x, b4.y, b4.z, b4.w};
#pragma unroll
            for (int i = 0; i < 4; ++i)
#pragma unroll
                for (int j = 0; j < 4; ++j)
                    acc[i][j] = fmaf(ar[i], br[j], acc[i][j]);
        }
    }

    float* P = part + (size_t)blockIdx.y * B_ * G4H;
#pragma unroll
    for (int i = 0; i < 4; ++i) {
        const int b = by * 4 + i;
        float4 v = {acc[i][0], acc[i][1], acc[i][2], acc[i][3]};
        *(float4*)(P + (size_t)b * G4H + n0 + nx * 4) = v;  // coalesced in n
    }
}

// Reduce KQ partials + xp, apply gates, write h, cT, hs, cs. 16384 threads.
__global__ __launch_bounds__(128) void lstm_point(
    const float* __restrict__ part, const float* __restrict__ xp,
    float* __restrict__ h, float* __restrict__ cT,
    float* __restrict__ hs, float* __restrict__ cs, int tl, int t)
{
    const int gi = blockIdx.x * 128 + threadIdx.x;   // 0..16383
    const int b  = gi >> 8;                          // 0..63
    const int j  = (gi & 255) * 4;                   // 0..1020

    const float* xpb = xp + ((size_t)tl * B_ + b) * G4H;
    float4 g0 = *(const float4*)(xpb + j);
    float4 g1 = *(const float4*)(xpb + H_ + j);
    float4 g2 = *(const float4*)(xpb + 2 * H_ + j);
    float4 g3 = *(const float4*)(xpb + 3 * H_ + j);
#pragma unroll
    for (int p = 0; p < KQ; ++p) {
        const float* P = part + ((size_t)p * B_ + b) * G4H;
        const float4 a = *(const float4*)(P + j);
        const float4 f = *(const float4*)(P + H_ + j);
        const float4 g = *(const float4*)(P + 2 * H_ + j);
        const float4 o = *(const float4*)(P + 3 * H_ + j);
        g0.x += a.x; g0.y += a.y; g0.z += a.z; g0.w += a.w;
        g1.x += f.x; g1.y += f.y; g1.z += f.z; g1.w += f.w;
        g2.x += g.x; g2.y += g.y; g2.z += g.z; g2.w += g.w;
        g3.x += o.x; g3.y += o.y; g3.z += o.z; g3.w += o.w;
    }

    const size_t sidx = (size_t)b * H_ + j;
    const float4 cp = *(const float4*)(cT + sidx);
    float cn[4], hn[4];
    const float ii[4] = {g0.x, g0.y, g0.z, g0.w};
    const float ff[4] = {g1.x, g1.y, g1.z, g1.w};
    const float gg[4] = {g2.x, g2.y, g2.z, g2.w};
    const float oo[4] = {g3.x, g3.y, g3.z, g3.w};
    const float cc[4] = {cp.x, cp.y, cp.z, cp.w};
#pragma unroll
    for (int q = 0; q < 4; ++q) {
        const float c2 = fmaf(sigm(ff[q]), cc[q], sigm(ii[q]) * tanh_fast(gg[q]));
        cn[q] = c2;
        hn[q] = sigm(oo[q]) * tanh_fast(c2);
    }
    const float4 cv = {cn[0], cn[1], cn[2], cn[3]};
    const float4 hv = {hn[0], hn[1], hn[2], hn[3]};
    *(float4*)(cT + sidx) = cv;
    *(float4*)(h + sidx) = hv;
    const size_t oidx = ((size_t)b * T_ + t) * H_ + j;
    *(float4*)(hs + oidx) = hv;
    *(float4*)(cs + oidx) = cv;
}

__global__ __launch_bounds__(256) void gather_last(
    const float* __restrict__ hs, const float* __restrict__ cs,
    const int* __restrict__ length,
    float* __restrict__ hl, float* __restrict__ cl)
{
    const int i = blockIdx.x * 256 + threadIdx.x;   // B*H total
    const int b = i >> 10;
    const int j = i & 1023;
    const int tt = length[b] - 1;
    const size_t src = ((size_t)b * T_ + tt) * H_ + j;
    hl[i] = hs[src];
    cl[i] = cs[src];
}

extern "C" void kernel_launch(void* const* d_in, const int* in_sizes, int n_in,
                              void* d_out, int out_size, void* d_ws, size_t ws_size,
                              hipStream_t stream)
{
    const float* X   = (const float*)d_in[0];
    const float* Wih = (const float*)d_in[1];
    const float* Whh = (const float*)d_in[2];
    const float* bih = (const float*)d_in[3];
    const float* bhh = (const float*)d_in[4];
    const int*   len = (const int*)d_in[5];

    float* out = (float*)d_out;
    float* hs = out;
    float* cs = hs + (size_t)B_ * T_ * H_;
    float* hl = cs + (size_t)B_ * T_ * H_;
    float* cl = hl + (size_t)B_ * H_;

    // ws layout: h | cT | WT | part | xp-chunk
    float* h    = (float*)d_ws;
    float* cT   = h + (size_t)B_ * H_;
    float* WT   = cT + (size_t)B_ * H_;
    float* part = WT + (size_t)H_ * G4H;
    float* xp   = part + (size_t)KQ * B_ * G4H;

    const size_t fixed_bytes =
        ((size_t)2 * B_ * H_ + (size_t)H_ * G4H + (size_t)KQ * B_ * G4H) * sizeof(float);
    const size_t per_t = (size_t)B_ * G4H * sizeof(float);   // 1 MiB per timestep

    int Tc = 1;
    if (ws_size > fixed_bytes + per_t) {
        size_t m = (ws_size - fixed_bytes) / per_t;
        Tc = (int)(m > (size_t)T_ ? (size_t)T_ : m);
    }

    hipMemsetAsync(h, 0, (size_t)2 * B_ * H_ * sizeof(float), stream);  // h, cT
    transpose_whh<<<dim3(64, 16), 256, 0, stream>>>(Whh, WT);

    for (int t0 = 0; t0 < T_; t0 += Tc) {
        const int clen = (T_ - t0 < Tc) ? (T_ - t0) : Tc;
        xproj_gemm<<<dim3(G4H / 64, clen), 256, 0, stream>>>(X, Wih, bih, bhh, xp, t0);
        for (int tl = 0; tl < clen; ++tl) {
            const int t = t0 + tl;
            step_gemm<<<dim3(64, KQ), 256, 0, stream>>>(WT, h, part);
            lstm_point<<<128, 128, 0, stream>>>(part, xp, h, cT, hs, cs, tl, t);
        }
    }
    gather_last<<<(B_ * H_) / 256, 256, 0, stream>>>(hs, cs, len, hl, cl);
}